// Round 4
// baseline (10256.698 us; speedup 1.0000x reference)
//
#include <hip/hip_runtime.h>
#include <hip/hip_bf16.h>
#include <stdint.h>
#include <cstdio>
#include <math.h>

// ---------------------------------------------------------------------------
// SpikingTradingAgent on MI355X — round 4: BIT-FAITHFUL to a float32 numpy
// reference. Key insight from rounds 1-3: three numerically different (and
// increasingly exact) implementations produced the IDENTICAL absmax error
// (0.625/32) -> the reference is sequential-f32 arithmetic and the error was
// the REFERENCE's own rounding vs my too-exact trajectories. So this round
// replicates f32 op-for-op:
//  * einsum('bi,pih->pbh'): f32 chain over i ASCENDING. spikes in {0,1} make
//    fma-vs-mul+add immaterial: chain == fl(acc + W) over active i. VALU only.
//  * mem = fl(fl(0.9f*mem) + fl(einsum+bias)); spike iff mem>=1.0f && !ref.
//  * encoder: k-seq FMA f32 GEMM with OpenBLAS-style kc=384 panel split,
//    sigmoid = 1/(1+CR_expf(-z)); spike compare in f32.
//  * acc: per-step 4-term p-ascending f32 chain, t-sequential adds, /32.
// Refractory (REFRACTORY=2 => 1-step block) encoded as mem == -0.0f.
// ---------------------------------------------------------------------------

typedef unsigned int u32;
typedef unsigned long long u64;

// workspace layout (bytes)
#define ENCT_OFF 0u                       // f32 [512][4096] (transposed)  8 MiB
#define BITS_OFF (8u << 20)               // u64 [32][512][64]             8 MiB
#define CB_OFF   (16u << 20)              // u32 [4][4096][1024]          64 MiB
#define HID_OFF  (80u << 20)              // f32 [4096][512]               8 MiB
#define WS_NEED  ((size_t)HID_OFF + (8u << 20))

// d_out layout (floats): out0 [4096][3] @0, out1 [4096][4] @12288,
// out2 (mean_spike_rate) [4096][1024] @28672
#define OUT1_F 12288
#define OUT2_F 28672

// ---------------------------------------------------------------------------
// Encoder, f32-faithful: z = x @ enc_W with k-sequential FMA chains and a
// kc=384 panel split (OpenBLAS sgemm GEMM_Q), + bias, sigmoid via CR expf.
// Output TRANSPOSED enc_T[i][b] for k_spike's coalesced reads.
// Wave: lane = b (64), 8 j's per wave.
// ---------------------------------------------------------------------------
__global__ __launch_bounds__(64) void k_genc(const float* __restrict__ x,
                                             const float* __restrict__ W,
                                             const float* __restrict__ bias,
                                             float* __restrict__ encT) {
  const int lane = threadIdx.x;
  const int bg = blockIdx.x & 63;   // b-group of 64
  const int jg = blockIdx.x >> 6;   // j-group of 8 (64 groups)
  const int b = bg * 64 + lane;
  const int j0 = jg * 8;
  const float* xr = x + (size_t)b * 512;
  float accA[8], accB[8];
#pragma unroll
  for (int u = 0; u < 8; ++u) { accA[u] = 0.0f; accB[u] = 0.0f; }
  for (int k = 0; k < 384; ++k) {
    float xv = xr[k];
#pragma unroll
    for (int u = 0; u < 8; ++u) accA[u] = fmaf(xv, W[k * 512 + j0 + u], accA[u]);
  }
  for (int k = 384; k < 512; ++k) {
    float xv = xr[k];
#pragma unroll
    for (int u = 0; u < 8; ++u) accB[u] = fmaf(xv, W[k * 512 + j0 + u], accB[u]);
  }
#pragma unroll
  for (int u = 0; u < 8; ++u) {
    float z = __fadd_rn(__fadd_rn(accA[u], accB[u]), bias[j0 + u]);
    float ef = (float)exp(-(double)z);          // == correctly-rounded expf
    float enc = 1.0f / (1.0f + ef);
    encT[(size_t)(j0 + u) * 4096 + b] = enc;
  }
}

// ---------------------------------------------------------------------------
// Spike train bits: bit b of word bitsT[t][i][b/64] = (noise[b][t][i] <
// enc[b][i]) in f32. lane = b -> __ballot IS the word. Per-lane noise rows
// get full cacheline reuse across consecutive i.
// ---------------------------------------------------------------------------
__global__ __launch_bounds__(64) void k_spike(const float* __restrict__ noise,
                                              const float* __restrict__ encT,
                                              u64* __restrict__ bitsT) {
  const int lane = threadIdx.x;
  const int t = blockIdx.x & 31;
  const int bw = blockIdx.x >> 5;   // 64 b-waves
  const int b = bw * 64 + lane;
  const float* nr = noise + ((size_t)b * 32 + t) * 512;
  for (int i0 = 0; i0 < 512; i0 += 4) {
    float4 nv = *(const float4*)(nr + i0);
    float e0 = encT[(size_t)(i0 + 0) * 4096 + b];
    float e1 = encT[(size_t)(i0 + 1) * 4096 + b];
    float e2 = encT[(size_t)(i0 + 2) * 4096 + b];
    float e3 = encT[(size_t)(i0 + 3) * 4096 + b];
    u64 m0 = __ballot(nv.x < e0);
    u64 m1 = __ballot(nv.y < e1);
    u64 m2 = __ballot(nv.z < e2);
    u64 m3 = __ballot(nv.w < e3);
    if (lane == 0) {
      u64* dst = bitsT + ((size_t)t * 512 + i0) * 64 + bw;
      dst[0] = m0; dst[64] = m1; dst[128] = m2; dst[192] = m3;
    }
  }
}

// ---------------------------------------------------------------------------
// pathway selection: softmax(x @ sel_W + sel_b) -> out1 f32 (value-level op;
// f64 accumulate rounds to ~CR f32, well within tolerance).
// ---------------------------------------------------------------------------
__global__ __launch_bounds__(256) void k_sel(const float* __restrict__ x,
                                             const float* __restrict__ selW,
                                             const float* __restrict__ selB,
                                             float* __restrict__ out1) {
  int b = blockIdx.x * 256 + threadIdx.x;
  const float* xr = x + (size_t)b * 512;
  double a0 = 0, a1 = 0, a2 = 0, a3 = 0;
  for (int k = 0; k < 512; ++k) {
    double xv = (double)xr[k];
    float4 w = *(const float4*)(selW + k * 4);
    a0 = fma(xv, (double)w.x, a0);
    a1 = fma(xv, (double)w.y, a1);
    a2 = fma(xv, (double)w.z, a2);
    a3 = fma(xv, (double)w.w, a3);
  }
  a0 += (double)selB[0]; a1 += (double)selB[1];
  a2 += (double)selB[2]; a3 += (double)selB[3];
  double m = fmax(fmax(a0, a1), fmax(a2, a3));
  double e0 = exp(a0 - m), e1 = exp(a1 - m), e2 = exp(a2 - m), e3 = exp(a3 - m);
  double inv = 1.0 / (e0 + e1 + e2 + e3);
  float4 wf = {(float)(e0 * inv), (float)(e1 * inv), (float)(e2 * inv), (float)(e3 * inv)};
  *(float4*)(out1 + (size_t)b * 4) = wf;
}

// ---------------------------------------------------------------------------
// Fused LIF, f32-faithful. Wave (64 threads): lane = b; owns (p, 64 h's, 64
// b's). Per t: i = 0..511 ascending; spf = {0,1} float broadcast from the
// spike bit-pair via v_cndmask (mask bit = lane = b); 64 W scalars (uniform
// s_loads) feed 64 independent fmacs: acc[h] = fl(acc[h] + spf*W[p,i,h]) --
// bit-identical to numpy's sequential-i f32 einsum chain. Then the f32
// membrane update in reference op order. Spike bits per (b,h) packed over t
// into u32, transposed via LDS for coalesced store.
// XCD swizzle pins each (p,h-block) W-slab (128KB) to one XCD's L2.
// ---------------------------------------------------------------------------
__global__ __launch_bounds__(64, 2) void k_lif(const float* __restrict__ W,
                                               const float* __restrict__ lifB,
                                               const u64* __restrict__ bitsT,
                                               u32* __restrict__ cb) {
  __shared__ u32 tr[64][65];
  const int lane = threadIdx.x;
  const int L = blockIdx.x;                 // 4096
  const int slab = (L & 7) * 8 + ((L >> 3) & 7);  // 0..63, pinned to XCD L&7
  const int bw = L >> 6;                    // 0..63
  const int p = slab >> 4;
  const int h0 = (slab & 15) * 64;
  const int b0 = bw * 64;
  const float* Wp = W + (size_t)p * 512 * 1024 + h0;
  const float* biasp = lifB + p * 1024 + h0;

  float mem[64], acc[64];
  u32 cbits[64];
#pragma unroll
  for (int h = 0; h < 64; ++h) { mem[h] = 0.0f; acc[h] = 0.0f; cbits[h] = 0u; }

#pragma unroll 1
  for (int t = 0; t < 32; ++t) {
    const u64* bt = bitsT + (size_t)t * 512 * 64 + bw;
#pragma unroll 1
    for (int i = 0; i < 512; ++i) {
      u64 m = bt[(size_t)i * 64];           // uniform -> s_load_dwordx2
      float spf;
      asm("v_cndmask_b32 %0, 0, 1.0, %1" : "=v"(spf) : "s"(m));
      const float* wrow = Wp + (size_t)i * 1024;   // uniform -> s_loads
#pragma unroll
      for (int h = 0; h < 64; ++h) acc[h] = fmaf(wrow[h], spf, acc[h]);
    }
    // membrane update, reference op order (all f32, no contraction)
#pragma unroll
    for (int h = 0; h < 64; ++h) {
      float c = __fadd_rn(acc[h], biasp[h]);
      float mo = mem[h];
      bool blocked = (__float_as_uint(mo) == 0x80000000u);
      float mn = __fadd_rn(__fmul_rn(mo, 0.9f), c);
      bool sp = (mn >= 1.0f) && (!blocked);
      mem[h] = sp ? -0.0f : mn;
      cbits[h] |= (sp ? 1u : 0u) << t;
      acc[h] = 0.0f;
    }
  }
  // transpose (h-major regs -> b-major store) via LDS, coalesced over h
#pragma unroll
  for (int h = 0; h < 64; ++h) tr[h][lane] = cbits[h];
  __syncthreads();
  for (int bi = 0; bi < 64; ++bi)
    cb[((size_t)p * 4096 + b0 + bi) * 1024 + h0 + lane] = tr[lane][bi];
}

// ---------------------------------------------------------------------------
// msr[b][h]: faithful f32: per t: s = p-ascending chain of spiked w's;
// acc = fl(acc + s); msr = acc/32 (exact).
// ---------------------------------------------------------------------------
__global__ __launch_bounds__(256) void k_reduce(const u32* __restrict__ cb,
                                                const float* __restrict__ w,
                                                float* __restrict__ msr) {
  int idx = blockIdx.x * 256 + threadIdx.x;  // 4194304
  int h = idx & 1023;
  int b = idx >> 10;
  float4 wv = *(const float4*)(w + (size_t)b * 4);
  u32 c0 = cb[((size_t)0 * 4096 + b) * 1024 + h];
  u32 c1 = cb[((size_t)1 * 4096 + b) * 1024 + h];
  u32 c2 = cb[((size_t)2 * 4096 + b) * 1024 + h];
  u32 c3 = cb[((size_t)3 * 4096 + b) * 1024 + h];
  float acc = 0.0f;
#pragma unroll
  for (int t = 0; t < 32; ++t) {
    float s = ((c0 >> t) & 1u) ? wv.x : 0.0f;
    s = __fadd_rn(s, ((c1 >> t) & 1u) ? wv.y : 0.0f);
    s = __fadd_rn(s, ((c2 >> t) & 1u) ? wv.z : 0.0f);
    s = __fadd_rn(s, ((c3 >> t) & 1u) ? wv.w : 0.0f);
    acc = __fadd_rn(acc, s);
  }
  msr[(size_t)b * 1024 + h] = acc * 0.03125f;  // /32: exact power of 2
}

// ---------------------------------------------------------------------------
// f32 GEMM + relu (head):  out = relu(A[M,K] @ W[K,N] + bias)
// ---------------------------------------------------------------------------
__global__ __launch_bounds__(256) void k_gemm_relu(const float* __restrict__ A, int lda,
                                                   const float* __restrict__ W, int ldw,
                                                   const float* __restrict__ bias,
                                                   float* __restrict__ out, int ldo, int K) {
  __shared__ float As[16][65];
  __shared__ float Bs[16][64];
  const int tid = threadIdx.x;
  const int tx = tid & 15, ty = tid >> 4;
  const int n0 = blockIdx.x * 64, m0 = blockIdx.y * 64;
  const int sm = tid >> 2, skq = tid & 3;
  float acc[4][4] = {};
  for (int k0 = 0; k0 < K; k0 += 16) {
    float4 av = *(const float4*)(A + (size_t)(m0 + sm) * lda + k0 + skq * 4);
    As[skq * 4 + 0][sm] = av.x;
    As[skq * 4 + 1][sm] = av.y;
    As[skq * 4 + 2][sm] = av.z;
    As[skq * 4 + 3][sm] = av.w;
#pragma unroll
    for (int j = 0; j < 4; ++j) {
      int k = j * 4 + (tid >> 6);
      int n = tid & 63;
      Bs[k][n] = W[(size_t)(k0 + k) * ldw + n0 + n];
    }
    __syncthreads();
#pragma unroll
    for (int k = 0; k < 16; ++k) {
      float a[4], bb[4];
#pragma unroll
      for (int i = 0; i < 4; ++i) a[i] = As[k][ty * 4 + i];
#pragma unroll
      for (int i = 0; i < 4; ++i) bb[i] = Bs[k][tx * 4 + i];
#pragma unroll
      for (int i = 0; i < 4; ++i)
#pragma unroll
        for (int ii = 0; ii < 4; ++ii) acc[i][ii] = fmaf(a[i], bb[ii], acc[i][ii]);
    }
    __syncthreads();
  }
#pragma unroll
  for (int i = 0; i < 4; ++i)
#pragma unroll
    for (int ii = 0; ii < 4; ++ii) {
      float v = fmaxf(acc[i][ii] + bias[n0 + tx * 4 + ii], 0.0f);
      out[(size_t)(m0 + ty * 4 + i) * ldo + n0 + tx * 4 + ii] = v;
    }
}

// ---------------------------------------------------------------------------
// out0 = hid @ out_W2 + b2   (one thread per b)
// ---------------------------------------------------------------------------
__global__ __launch_bounds__(256) void k_head2(const float* __restrict__ hid,
                                               const float* __restrict__ W2,
                                               const float* __restrict__ b2,
                                               float* __restrict__ out0) {
  __shared__ float w2s[512][3];
  int tid = threadIdx.x;
  for (int i = tid; i < 1536; i += 256) ((float*)w2s)[i] = W2[i];
  __syncthreads();
  int b = blockIdx.x * 256 + tid;
  const float* hr = hid + (size_t)b * 512;
  float a0 = 0, a1 = 0, a2 = 0;
  for (int j = 0; j < 512; ++j) {
    float h = hr[j];
    a0 = fmaf(h, w2s[j][0], a0);
    a1 = fmaf(h, w2s[j][1], a1);
    a2 = fmaf(h, w2s[j][2], a2);
  }
  out0[b * 3 + 0] = a0 + b2[0];
  out0[b * 3 + 1] = a1 + b2[1];
  out0[b * 3 + 2] = a2 + b2[2];
}

// ---------------------------------------------------------------------------
extern "C" void kernel_launch(void* const* d_in, const int* in_sizes, int n_in,
                              void* d_out, int out_size, void* d_ws, size_t ws_size,
                              hipStream_t stream) {
  const float* x = (const float*)d_in[0];
  const float* noise = (const float*)d_in[1];
  const float* encW = (const float*)d_in[3];
  const float* encB = (const float*)d_in[4];
  const float* selW = (const float*)d_in[5];
  const float* selB = (const float*)d_in[6];
  const float* lifW = (const float*)d_in[7];
  const float* lifB = (const float*)d_in[8];
  const float* W1 = (const float*)d_in[9];
  const float* b1 = (const float*)d_in[10];
  const float* W2 = (const float*)d_in[11];
  const float* b2 = (const float*)d_in[12];
  float* out = (float*)d_out;
  unsigned char* ws = (unsigned char*)d_ws;

  if (ws_size < WS_NEED) {
    fprintf(stderr, "kernel_launch: ws too small (%zu < %zu)\n", ws_size, (size_t)WS_NEED);
    return;
  }

  float* encT = (float*)(ws + ENCT_OFF);
  u64* bitsT = (u64*)(ws + BITS_OFF);
  u32* cb = (u32*)(ws + CB_OFF);
  float* hid = (float*)(ws + HID_OFF);

  // 1. encoder (f32-faithful, kc=384 panel split, CR sigmoid) -> enc_T
  k_genc<<<dim3(4096), 64, 0, stream>>>(x, encW, encB, encT);
  // 2. pathway weights -> out1 (f32)
  k_sel<<<dim3(16), 256, 0, stream>>>(x, selW, selB, out + OUT1_F);
  // 3. spike bits, f32 compare, ballot -> [t][i][b]
  k_spike<<<dim3(2048), 64, 0, stream>>>(noise, encT, bitsT);
  // 4. fused LIF, sequential-i f32 chain (dominant)
  k_lif<<<dim3(4096), 64, 0, stream>>>(lifW, lifB, bitsT, cb);
  // 5. mean spike rate (faithful f32 p/t chains) -> out2
  k_reduce<<<dim3(16384), 256, 0, stream>>>(cb, out + OUT1_F, out + OUT2_F);
  // 6. hid = relu(msr @ W1 + b1)
  k_gemm_relu<<<dim3(8, 64), 256, 0, stream>>>(out + OUT2_F, 1024, W1, 512, b1, hid, 512, 1024);
  // 7. out0 = hid @ W2 + b2
  k_head2<<<dim3(16), 256, 0, stream>>>(hid, W2, b2, out);
}

// Round 5
// 6822.266 us; speedup vs baseline: 1.5034x; 1.5034x over previous
//
#include <hip/hip_runtime.h>
#include <hip/hip_bf16.h>
#include <stdint.h>
#include <cstdio>
#include <math.h>

// ---------------------------------------------------------------------------
// SpikingTradingAgent on MI355X — round 5.
// Numerics FROZEN from round 4 (passed, absmax 1.07e-2): f32-faithful
// sequential-i einsum chain, f32 membrane update in reference op order,
// -0.0 refractory encoding, CR-exp sigmoid encoder, ballot spike bits.
// This round: k_lif restructured for occupancy + s_load pipelining.
//   wave tile 64h -> 16h  (regs ~200 -> ~60  => 8 waves/SIMD)
//   W row/i 256B -> 64B   (16 SGPRs => unroll-4 software pipeline fits SGPRs)
//   masks: [t][bw][i] contiguous per wave (merged s_load_dwordx8)
//   no LDS transpose (lane already owns 16 consecutive h) => LDS 0
//   XCD swizzle: 32 slabs (1MB W) pinned per XCD L2.
// Arithmetic per (b,h) trajectory is BIT-IDENTICAL to round 4.
// ---------------------------------------------------------------------------

typedef unsigned int u32;
typedef unsigned long long u64;

// workspace layout (bytes)
#define ENCT_OFF 0u                       // f32 [512][4096] (transposed)  8 MiB
#define BITS_OFF (8u << 20)               // u64 [32][64][512]             8 MiB
#define CB_OFF   (16u << 20)              // u32 [4][4096][1024]          64 MiB
#define HID_OFF  (80u << 20)              // f32 [4096][512]               8 MiB
#define WS_NEED  ((size_t)HID_OFF + (8u << 20))

// d_out layout (floats): out0 [4096][3] @0, out1 [4096][4] @12288,
// out2 (mean_spike_rate) [4096][1024] @28672
#define OUT1_F 12288
#define OUT2_F 28672

// ---------------------------------------------------------------------------
// Encoder, f32-faithful: z = x @ enc_W, k-sequential FMA chains, kc=384 panel
// split, + bias, sigmoid via CR expf. Output transposed enc_T[i][b].
// ---------------------------------------------------------------------------
__global__ __launch_bounds__(64) void k_genc(const float* __restrict__ x,
                                             const float* __restrict__ W,
                                             const float* __restrict__ bias,
                                             float* __restrict__ encT) {
  const int lane = threadIdx.x;
  const int bg = blockIdx.x & 63;   // b-group of 64
  const int jg = blockIdx.x >> 6;   // j-group of 8 (64 groups)
  const int b = bg * 64 + lane;
  const int j0 = jg * 8;
  const float* xr = x + (size_t)b * 512;
  float accA[8], accB[8];
#pragma unroll
  for (int u = 0; u < 8; ++u) { accA[u] = 0.0f; accB[u] = 0.0f; }
  for (int k = 0; k < 384; ++k) {
    float xv = xr[k];
#pragma unroll
    for (int u = 0; u < 8; ++u) accA[u] = fmaf(xv, W[k * 512 + j0 + u], accA[u]);
  }
  for (int k = 384; k < 512; ++k) {
    float xv = xr[k];
#pragma unroll
    for (int u = 0; u < 8; ++u) accB[u] = fmaf(xv, W[k * 512 + j0 + u], accB[u]);
  }
#pragma unroll
  for (int u = 0; u < 8; ++u) {
    float z = __fadd_rn(__fadd_rn(accA[u], accB[u]), bias[j0 + u]);
    float ef = (float)exp(-(double)z);          // == correctly-rounded expf
    float enc = 1.0f / (1.0f + ef);
    encT[(size_t)(j0 + u) * 4096 + b] = enc;
  }
}

// ---------------------------------------------------------------------------
// Spike bits: bit b of bitsT[t][bw][i] = (noise[b][t][i] < enc[b][i]), f32.
// lane = b -> __ballot IS the word. New wave-contiguous [t][bw][i] layout.
// ---------------------------------------------------------------------------
__global__ __launch_bounds__(64) void k_spike(const float* __restrict__ noise,
                                              const float* __restrict__ encT,
                                              u64* __restrict__ bitsT) {
  const int lane = threadIdx.x;
  const int t = blockIdx.x & 31;
  const int bw = blockIdx.x >> 5;   // 64 b-waves
  const int b = bw * 64 + lane;
  const float* nr = noise + ((size_t)b * 32 + t) * 512;
  u64* dst = bitsT + ((size_t)t * 64 + bw) * 512;
  for (int i0 = 0; i0 < 512; i0 += 4) {
    float4 nv = *(const float4*)(nr + i0);
    float e0 = encT[(size_t)(i0 + 0) * 4096 + b];
    float e1 = encT[(size_t)(i0 + 1) * 4096 + b];
    float e2 = encT[(size_t)(i0 + 2) * 4096 + b];
    float e3 = encT[(size_t)(i0 + 3) * 4096 + b];
    u64 m0 = __ballot(nv.x < e0);
    u64 m1 = __ballot(nv.y < e1);
    u64 m2 = __ballot(nv.z < e2);
    u64 m3 = __ballot(nv.w < e3);
    if (lane == 0) {
      dst[i0 + 0] = m0; dst[i0 + 1] = m1; dst[i0 + 2] = m2; dst[i0 + 3] = m3;
    }
  }
}

// ---------------------------------------------------------------------------
// pathway selection: softmax(x @ sel_W + sel_b) -> out1 f32
// ---------------------------------------------------------------------------
__global__ __launch_bounds__(256) void k_sel(const float* __restrict__ x,
                                             const float* __restrict__ selW,
                                             const float* __restrict__ selB,
                                             float* __restrict__ out1) {
  int b = blockIdx.x * 256 + threadIdx.x;
  const float* xr = x + (size_t)b * 512;
  double a0 = 0, a1 = 0, a2 = 0, a3 = 0;
  for (int k = 0; k < 512; ++k) {
    double xv = (double)xr[k];
    float4 w = *(const float4*)(selW + k * 4);
    a0 = fma(xv, (double)w.x, a0);
    a1 = fma(xv, (double)w.y, a1);
    a2 = fma(xv, (double)w.z, a2);
    a3 = fma(xv, (double)w.w, a3);
  }
  a0 += (double)selB[0]; a1 += (double)selB[1];
  a2 += (double)selB[2]; a3 += (double)selB[3];
  double m = fmax(fmax(a0, a1), fmax(a2, a3));
  double e0 = exp(a0 - m), e1 = exp(a1 - m), e2 = exp(a2 - m), e3 = exp(a3 - m);
  double inv = 1.0 / (e0 + e1 + e2 + e3);
  float4 wf = {(float)(e0 * inv), (float)(e1 * inv), (float)(e2 * inv), (float)(e3 * inv)};
  *(float4*)(out1 + (size_t)b * 4) = wf;
}

// ---------------------------------------------------------------------------
// Fused LIF, f32-faithful, 16h wave tile. Wave: lane = b (64 b's), 16 h's.
// Per i: 1 s_load_dwordx16 (64B W row) + mask bit -> spf {0,1} via cndmask;
// 16 fmac: acc[h] = fl(acc[h] + spf*W[p,i,h]) — bit-identical to numpy's
// sequential-i f32 chain. Unroll-4 software-pipelines the scalar loads.
// Membrane update in reference op order. No LDS; direct uint4 stores.
// ---------------------------------------------------------------------------
__global__ __launch_bounds__(64) void k_lif(const float* __restrict__ W,
                                            const float* __restrict__ lifB,
                                            const u64* __restrict__ bitsT,
                                            u32* __restrict__ cb) {
  const int lane = threadIdx.x;
  const int bid = blockIdx.x;                      // 16384
  const int slab = (bid & 7) * 32 + ((bid >> 3) & 31);  // 0..255, XCD-pinned
  const int bw = bid >> 8;                         // 0..63
  const int p = slab >> 6;
  const int h0 = (slab & 63) * 16;
  const int b0 = bw * 64;
  const float* Wp = W + (size_t)p * 512 * 1024 + h0;    // row stride 1024
  const float* biasp = lifB + p * 1024 + h0;

  float mem[16], acc[16];
  u32 cbits[16];
  float bias_r[16];
#pragma unroll
  for (int h = 0; h < 16; ++h) {
    mem[h] = 0.0f; acc[h] = 0.0f; cbits[h] = 0u;
    bias_r[h] = biasp[h];
  }

#pragma unroll 1
  for (int t = 0; t < 32; ++t) {
    const u64* bt = bitsT + ((size_t)t * 64 + bw) * 512;
#pragma unroll 4
    for (int i = 0; i < 512; ++i) {
      u64 m = bt[i];                         // uniform -> s_load (merged x4)
      float spf;
      asm("v_cndmask_b32 %0, 0, 1.0, %1" : "=v"(spf) : "s"(m));
      const float* wrow = Wp + (size_t)i * 1024;  // uniform -> s_load_dwordx16
#pragma unroll
      for (int h = 0; h < 16; ++h) acc[h] = fmaf(wrow[h], spf, acc[h]);
    }
    // membrane update, reference op order (all f32, no contraction)
#pragma unroll
    for (int h = 0; h < 16; ++h) {
      float c = __fadd_rn(acc[h], bias_r[h]);
      float mo = mem[h];
      bool blocked = (__float_as_uint(mo) == 0x80000000u);
      float mn = __fadd_rn(__fmul_rn(mo, 0.9f), c);
      bool sp = (mn >= 1.0f) && (!blocked);
      mem[h] = sp ? -0.0f : mn;
      cbits[h] |= (sp ? 1u : 0u) << t;
      acc[h] = 0.0f;
    }
  }
  // store: lane owns (b = b0+lane, h = h0..h0+15) -> 16 consecutive u32
  u32* dst = cb + ((size_t)p * 4096 + b0 + lane) * 1024 + h0;
#pragma unroll
  for (int q = 0; q < 4; ++q) {
    uint4 v = {cbits[q * 4 + 0], cbits[q * 4 + 1], cbits[q * 4 + 2], cbits[q * 4 + 3]};
    *(uint4*)(dst + q * 4) = v;
  }
}

// ---------------------------------------------------------------------------
// msr[b][h]: faithful f32: per t: s = p-ascending chain; acc = fl(acc+s); /32.
// ---------------------------------------------------------------------------
__global__ __launch_bounds__(256) void k_reduce(const u32* __restrict__ cb,
                                                const float* __restrict__ w,
                                                float* __restrict__ msr) {
  int idx = blockIdx.x * 256 + threadIdx.x;  // 4194304
  int h = idx & 1023;
  int b = idx >> 10;
  float4 wv = *(const float4*)(w + (size_t)b * 4);
  u32 c0 = cb[((size_t)0 * 4096 + b) * 1024 + h];
  u32 c1 = cb[((size_t)1 * 4096 + b) * 1024 + h];
  u32 c2 = cb[((size_t)2 * 4096 + b) * 1024 + h];
  u32 c3 = cb[((size_t)3 * 4096 + b) * 1024 + h];
  float acc = 0.0f;
#pragma unroll
  for (int t = 0; t < 32; ++t) {
    float s = ((c0 >> t) & 1u) ? wv.x : 0.0f;
    s = __fadd_rn(s, ((c1 >> t) & 1u) ? wv.y : 0.0f);
    s = __fadd_rn(s, ((c2 >> t) & 1u) ? wv.z : 0.0f);
    s = __fadd_rn(s, ((c3 >> t) & 1u) ? wv.w : 0.0f);
    acc = __fadd_rn(acc, s);
  }
  msr[(size_t)b * 1024 + h] = acc * 0.03125f;  // /32 exact
}

// ---------------------------------------------------------------------------
// f32 GEMM + relu (head):  out = relu(A[M,K] @ W[K,N] + bias)
// ---------------------------------------------------------------------------
__global__ __launch_bounds__(256) void k_gemm_relu(const float* __restrict__ A, int lda,
                                                   const float* __restrict__ W, int ldw,
                                                   const float* __restrict__ bias,
                                                   float* __restrict__ out, int ldo, int K) {
  __shared__ float As[16][65];
  __shared__ float Bs[16][64];
  const int tid = threadIdx.x;
  const int tx = tid & 15, ty = tid >> 4;
  const int n0 = blockIdx.x * 64, m0 = blockIdx.y * 64;
  const int sm = tid >> 2, skq = tid & 3;
  float acc[4][4] = {};
  for (int k0 = 0; k0 < K; k0 += 16) {
    float4 av = *(const float4*)(A + (size_t)(m0 + sm) * lda + k0 + skq * 4);
    As[skq * 4 + 0][sm] = av.x;
    As[skq * 4 + 1][sm] = av.y;
    As[skq * 4 + 2][sm] = av.z;
    As[skq * 4 + 3][sm] = av.w;
#pragma unroll
    for (int j = 0; j < 4; ++j) {
      int k = j * 4 + (tid >> 6);
      int n = tid & 63;
      Bs[k][n] = W[(size_t)(k0 + k) * ldw + n0 + n];
    }
    __syncthreads();
#pragma unroll
    for (int k = 0; k < 16; ++k) {
      float a[4], bb[4];
#pragma unroll
      for (int i = 0; i < 4; ++i) a[i] = As[k][ty * 4 + i];
#pragma unroll
      for (int i = 0; i < 4; ++i) bb[i] = Bs[k][tx * 4 + i];
#pragma unroll
      for (int i = 0; i < 4; ++i)
#pragma unroll
        for (int ii = 0; ii < 4; ++ii) acc[i][ii] = fmaf(a[i], bb[ii], acc[i][ii]);
    }
    __syncthreads();
  }
#pragma unroll
  for (int i = 0; i < 4; ++i)
#pragma unroll
    for (int ii = 0; ii < 4; ++ii) {
      float v = fmaxf(acc[i][ii] + bias[n0 + tx * 4 + ii], 0.0f);
      out[(size_t)(m0 + ty * 4 + i) * ldo + n0 + tx * 4 + ii] = v;
    }
}

// ---------------------------------------------------------------------------
// out0 = hid @ out_W2 + b2   (one thread per b)
// ---------------------------------------------------------------------------
__global__ __launch_bounds__(256) void k_head2(const float* __restrict__ hid,
                                               const float* __restrict__ W2,
                                               const float* __restrict__ b2,
                                               float* __restrict__ out0) {
  __shared__ float w2s[512][3];
  int tid = threadIdx.x;
  for (int i = tid; i < 1536; i += 256) ((float*)w2s)[i] = W2[i];
  __syncthreads();
  int b = blockIdx.x * 256 + tid;
  const float* hr = hid + (size_t)b * 512;
  float a0 = 0, a1 = 0, a2 = 0;
  for (int j = 0; j < 512; ++j) {
    float h = hr[j];
    a0 = fmaf(h, w2s[j][0], a0);
    a1 = fmaf(h, w2s[j][1], a1);
    a2 = fmaf(h, w2s[j][2], a2);
  }
  out0[b * 3 + 0] = a0 + b2[0];
  out0[b * 3 + 1] = a1 + b2[1];
  out0[b * 3 + 2] = a2 + b2[2];
}

// ---------------------------------------------------------------------------
extern "C" void kernel_launch(void* const* d_in, const int* in_sizes, int n_in,
                              void* d_out, int out_size, void* d_ws, size_t ws_size,
                              hipStream_t stream) {
  const float* x = (const float*)d_in[0];
  const float* noise = (const float*)d_in[1];
  const float* encW = (const float*)d_in[3];
  const float* encB = (const float*)d_in[4];
  const float* selW = (const float*)d_in[5];
  const float* selB = (const float*)d_in[6];
  const float* lifW = (const float*)d_in[7];
  const float* lifB = (const float*)d_in[8];
  const float* W1 = (const float*)d_in[9];
  const float* b1 = (const float*)d_in[10];
  const float* W2 = (const float*)d_in[11];
  const float* b2 = (const float*)d_in[12];
  float* out = (float*)d_out;
  unsigned char* ws = (unsigned char*)d_ws;

  if (ws_size < WS_NEED) {
    fprintf(stderr, "kernel_launch: ws too small (%zu < %zu)\n", ws_size, (size_t)WS_NEED);
    return;
  }

  float* encT = (float*)(ws + ENCT_OFF);
  u64* bitsT = (u64*)(ws + BITS_OFF);
  u32* cb = (u32*)(ws + CB_OFF);
  float* hid = (float*)(ws + HID_OFF);

  // 1. encoder (f32-faithful) -> enc_T
  k_genc<<<dim3(4096), 64, 0, stream>>>(x, encW, encB, encT);
  // 2. pathway weights -> out1 (f32)
  k_sel<<<dim3(16), 256, 0, stream>>>(x, selW, selB, out + OUT1_F);
  // 3. spike bits, f32 compare, ballot -> [t][bw][i]
  k_spike<<<dim3(2048), 64, 0, stream>>>(noise, encT, bitsT);
  // 4. fused LIF, sequential-i f32 chain (dominant)
  k_lif<<<dim3(16384), 64, 0, stream>>>(lifW, lifB, bitsT, cb);
  // 5. mean spike rate (faithful f32 p/t chains) -> out2
  k_reduce<<<dim3(16384), 256, 0, stream>>>(cb, out + OUT1_F, out + OUT2_F);
  // 6. hid = relu(msr @ W1 + b1)
  k_gemm_relu<<<dim3(8, 64), 256, 0, stream>>>(out + OUT2_F, 1024, W1, 512, b1, hid, 512, 1024);
  // 7. out0 = hid @ W2 + b2
  k_head2<<<dim3(16), 256, 0, stream>>>(hid, W2, b2, out);
}